// Round 9
// baseline (252.149 us; speedup 1.0000x reference)
//
#include <hip/hip_runtime.h>

#define DD 128

typedef _Float16 f16;
typedef __attribute__((ext_vector_type(8))) _Float16 v8h;
typedef __attribute__((ext_vector_type(4))) _Float16 v4h;
typedef __attribute__((ext_vector_type(4))) float f32x4;

static inline int cdiv(int a, int b) { return (a + b - 1) / b; }

// ---------------- small utility ----------------

__global__ __launch_bounds__(256) void zero_kernel(int* __restrict__ p, int n) {
    int i = blockIdx.x * 256 + threadIdx.x;
    if (i < n) p[i] = 0;
}

// ---------------- CSR build ----------------

__global__ __launch_bounds__(256) void count_kernel(const int* __restrict__ dst, int E,
                                                    int* __restrict__ cnt) {
    int e = blockIdx.x * 256 + threadIdx.x;
    if (e < E) atomicAdd(&cnt[dst[e]], 1);
}

__global__ __launch_bounds__(256) void scan1(const int* __restrict__ cnt, int N,
                                             int* __restrict__ bsum) {
    __shared__ int s[256];
    int i = blockIdx.x * 256 + threadIdx.x;
    s[threadIdx.x] = (i < N) ? cnt[i] : 0;
    __syncthreads();
    for (int off = 128; off > 0; off >>= 1) {
        if (threadIdx.x < off) s[threadIdx.x] += s[threadIdx.x + off];
        __syncthreads();
    }
    if (threadIdx.x == 0) bsum[blockIdx.x] = s[0];
}

__global__ __launch_bounds__(512) void scan2(const int* __restrict__ bsum, int NB,
                                             int* __restrict__ boff) {
    __shared__ int s[512];
    int t = threadIdx.x;
    int v = (t < NB) ? bsum[t] : 0;
    s[t] = v;
    __syncthreads();
    for (int off = 1; off < 512; off <<= 1) {
        int x = (t >= off) ? s[t - off] : 0;
        __syncthreads();
        s[t] += x;
        __syncthreads();
    }
    if (t < NB) boff[t] = s[t] - v;  // exclusive
}

__global__ __launch_bounds__(256) void scan3(const int* __restrict__ cnt,
                                             const int* __restrict__ boff, int N,
                                             int* __restrict__ off) {
    __shared__ int s[256];
    int t = threadIdx.x;
    int i = blockIdx.x * 256 + t;
    int v = (i < N) ? cnt[i] : 0;
    s[t] = v;
    __syncthreads();
    for (int o = 1; o < 256; o <<= 1) {
        int x = (t >= o) ? s[t - o] : 0;
        __syncthreads();
        s[t] += x;
        __syncthreads();
    }
    int excl = s[t] - v + boff[blockIdx.x];
    if (i < N) off[i] = excl;
    if (i == N - 1) off[N] = excl + v;
}

__global__ __launch_bounds__(256) void fill_kernel(const int* __restrict__ src,
                                                   const int* __restrict__ dst, int E,
                                                   const int* __restrict__ off,
                                                   int* __restrict__ cnt,
                                                   int* __restrict__ csr) {
    int e = blockIdx.x * 256 + threadIdx.x;
    if (e < E) {
        int d = dst[e];
        int p = atomicSub(&cnt[d], 1) - 1;  // unique slot within [0, deg)
        csr[off[d] + p] = src[e];
    }
}

// ---------------- fp32 -> f16 conversions ----------------

__global__ __launch_bounds__(256) void cvt_w_kernel(const float* __restrict__ W0,
                                                    const float* __restrict__ W1,
                                                    const float* __restrict__ W2,
                                                    const float* __restrict__ W3,
                                                    const float* __restrict__ W4,
                                                    const float* __restrict__ W5,
                                                    f16* __restrict__ out) {
    int mat = blockIdx.x >> 4;  // 16 blocks per matrix (16384 elems / (256*4))
    const float* W = mat == 0 ? W0 : mat == 1 ? W1 : mat == 2 ? W2
                   : mat == 3 ? W3 : mat == 4 ? W4 : W5;
    int base = (blockIdx.x & 15) * 1024 + threadIdx.x * 4;
    float4 v = *(const float4*)(W + base);
    v4h o;
    o[0] = (f16)v.x; o[1] = (f16)v.y; o[2] = (f16)v.z; o[3] = (f16)v.w;
    *(v4h*)(out + mat * 16384 + base) = o;
}

__global__ __launch_bounds__(256) void cvt_x_kernel(const float* __restrict__ x,
                                                    f16* __restrict__ out, int n8) {
    int i = blockIdx.x * 256 + threadIdx.x;
    if (i >= n8) return;
    float4 a = *(const float4*)(x + (size_t)i * 8);
    float4 b = *(const float4*)(x + (size_t)i * 8 + 4);
    v8h r;
    r[0] = (f16)a.x; r[1] = (f16)a.y; r[2] = (f16)a.z; r[3] = (f16)a.w;
    r[4] = (f16)b.x; r[5] = (f16)b.y; r[6] = (f16)b.z; r[7] = (f16)b.w;
    *(v8h*)(out + (size_t)i * 8) = r;
}

// ---------------- aggregation: mean of gathered h rows ----------------
// Wave per node; 4 groups x 16 lanes; each group gathers a full 256B row
// (16 lanes x 16B), groups stride the edge list by 4. Round-4 exact form:
// simple inner loop (compiler pipelines it); explicit pipelining (r6),
// batching (r7), and grid-stride (r8) all regressed.

__global__ __launch_bounds__(256) void aggregate_kernel(const f16* __restrict__ h,
                                                        const int* __restrict__ off,
                                                        const int* __restrict__ csr,
                                                        f16* __restrict__ mean, int N) {
    int n = blockIdx.x * 4 + (threadIdx.x >> 6);
    int l = threadIdx.x & 63;
    int g = l >> 4, c = l & 15;
    if (n >= N) return;
    int s = off[n], e = off[n + 1];
    float acc[8] = {0.f, 0.f, 0.f, 0.f, 0.f, 0.f, 0.f, 0.f};
    for (int i = s + g; i < e; i += 4) {
        int idx = csr[i];
        v8h v = *(const v8h*)(h + (size_t)idx * DD + c * 8);
#pragma unroll
        for (int j = 0; j < 8; ++j) acc[j] += (float)v[j];
    }
    // reduce across the 4 groups (lanes l, l^16, l^32, l^48)
#pragma unroll
    for (int j = 0; j < 8; ++j) {
        acc[j] += __shfl_xor(acc[j], 16);
        acc[j] += __shfl_xor(acc[j], 32);
    }
    int deg = e - s;
    float inv = 1.0f / (float)(deg > 0 ? deg : 1);
    if (g == 0) {
        v8h o;
#pragma unroll
        for (int j = 0; j < 8; ++j) o[j] = (f16)(acc[j] * inv);
        *(v8h*)(mean + (size_t)n * DD + c * 8) = o;
    }
}

// ---------------- shared GEMM helpers ----------------
// TRANSPOSED MFMA scheme: compute OUT^T = W * A^T by passing W as the
// first (A) operand and the input rows as the second (B) operand.
// mfma_f32_16x16x32_f16 fragment layouts (both operands identical per-lane):
//   frag lane l -> matrix[idx=l&15][k=(l>>4)*8+j], 8 contig f16
//   D lane l reg j -> out_col=(l>>4)*4+j, out_row=l&15
// => each lane's f32x4 acc covers 4 CONTIGUOUS output columns of one row:
//    packed 8B/16B stores instead of 64 scalar 2B stores (round-9 change).

// Stage 128x128 f16 W into LDS, chunk-swizzled: chunk (16B) sc = c16 ^ (col&7)
__device__ inline void stage_w(const f16* __restrict__ Wg, f16* __restrict__ smem, int t) {
#pragma unroll
    for (int i = 0; i < 8; ++i) {
        int idx16 = i * 256 + t;
        int col = idx16 >> 4, c16 = idx16 & 15;
        int sc = c16 ^ (col & 7);
        uint4 v = *(const uint4*)(Wg + idx16 * 8);
        *(uint4*)(smem + col * DD + sc * 8) = v;
    }
}

__device__ inline v8h read_b(const f16* __restrict__ smem, int ct, int ki, int l) {
    int col = ct * 16 + (l & 15);
    int c16 = ki * 4 + (l >> 4);
    int sc = c16 ^ (col & 7);
    return *(const v8h*)(smem + col * DD + sc * 8);
}

__device__ inline v8h load_frag16(const f16* __restrict__ A, int row, int kb, int M) {
    if (row >= M) {
        v8h z = {};
        return z;
    }
    return *(const v8h*)(A + (size_t)row * DD + kb);
}

// ---------------- projection GEMM: OUT = relu(A @ W^T + bias) ----------------

__global__ __launch_bounds__(256) void proj_gemm(const f16* __restrict__ A,
                                                 const f16* __restrict__ W1,
                                                 const float* __restrict__ bias,
                                                 f16* __restrict__ OUT, int M) {
    __shared__ f16 WS[DD * DD];
    int t = threadIdx.x, l = t & 63, w = t >> 6;
    int row0 = blockIdx.x * 128 + w * 32;
    int r = l & 15, cg = l >> 4;

    stage_w(W1, WS, t);

    v8h af[2][4];
#pragma unroll
    for (int rt = 0; rt < 2; ++rt)
#pragma unroll
        for (int ki = 0; ki < 4; ++ki)
            af[rt][ki] = load_frag16(A, row0 + rt * 16 + r, ki * 32 + cg * 8, M);
    __syncthreads();

    const f32x4* bias4 = (const f32x4*)bias;
    f32x4 acc[2][8];
#pragma unroll
    for (int ct = 0; ct < 8; ++ct) {
        f32x4 bv = bias4[ct * 4 + cg];  // cols ct*16+cg*4 .. +3
        acc[0][ct] = bv;
        acc[1][ct] = bv;
    }

#pragma unroll
    for (int ct = 0; ct < 8; ++ct)
#pragma unroll
        for (int ki = 0; ki < 4; ++ki) {
            v8h b = read_b(WS, ct, ki, l);
            acc[0][ct] = __builtin_amdgcn_mfma_f32_16x16x32_f16(b, af[0][ki], acc[0][ct], 0, 0, 0);
            acc[1][ct] = __builtin_amdgcn_mfma_f32_16x16x32_f16(b, af[1][ki], acc[1][ct], 0, 0, 0);
        }

    // epilogue: lane l -> row=row0+rt*16+r, cols ct*16+cg*4+[0..3] (packed 8B)
#pragma unroll
    for (int rt = 0; rt < 2; ++rt) {
        int row = row0 + rt * 16 + r;
        if (row < M) {
#pragma unroll
            for (int ct = 0; ct < 8; ++ct) {
                v4h p;
#pragma unroll
                for (int j = 0; j < 4; ++j) p[j] = (f16)fmaxf(acc[rt][ct][j], 0.f);
                *(v4h*)(OUT + (size_t)row * DD + ct * 16 + cg * 4) = p;
            }
        }
    }
}

// ---------------- dual GEMM: OUT = act(A @ Wl^T + bias + B @ Wr^T) ----------------
// 32KB LDS, restage between the two weight matrices (round-4 proven form).

template <typename TO, bool RELU>
__global__ __launch_bounds__(256) void dual_gemm(const f16* __restrict__ A,
                                                 const f16* __restrict__ Wl,
                                                 const float* __restrict__ bias,
                                                 const f16* __restrict__ B,
                                                 const f16* __restrict__ Wr,
                                                 TO* __restrict__ OUT, int M) {
    __shared__ f16 WS[DD * DD];
    int t = threadIdx.x, l = t & 63, w = t >> 6;
    int row0 = blockIdx.x * 128 + w * 32;
    int r = l & 15, cg = l >> 4;

    stage_w(Wl, WS, t);

    v8h afA[2][4], afB[2][4];
#pragma unroll
    for (int rt = 0; rt < 2; ++rt)
#pragma unroll
        for (int ki = 0; ki < 4; ++ki) {
            int row = row0 + rt * 16 + r, kb = ki * 32 + cg * 8;
            afA[rt][ki] = load_frag16(A, row, kb, M);
            afB[rt][ki] = load_frag16(B, row, kb, M);
        }
    __syncthreads();

    const f32x4* bias4 = (const f32x4*)bias;
    f32x4 acc[2][8];
#pragma unroll
    for (int ct = 0; ct < 8; ++ct) {
        f32x4 bv = bias4[ct * 4 + cg];
        acc[0][ct] = bv;
        acc[1][ct] = bv;
    }

#pragma unroll
    for (int ct = 0; ct < 8; ++ct)
#pragma unroll
        for (int ki = 0; ki < 4; ++ki) {
            v8h b = read_b(WS, ct, ki, l);
            acc[0][ct] = __builtin_amdgcn_mfma_f32_16x16x32_f16(b, afA[0][ki], acc[0][ct], 0, 0, 0);
            acc[1][ct] = __builtin_amdgcn_mfma_f32_16x16x32_f16(b, afA[1][ki], acc[1][ct], 0, 0, 0);
        }

    __syncthreads();  // all waves done reading Wl
    stage_w(Wr, WS, t);
    __syncthreads();

#pragma unroll
    for (int ct = 0; ct < 8; ++ct)
#pragma unroll
        for (int ki = 0; ki < 4; ++ki) {
            v8h b = read_b(WS, ct, ki, l);
            acc[0][ct] = __builtin_amdgcn_mfma_f32_16x16x32_f16(b, afB[0][ki], acc[0][ct], 0, 0, 0);
            acc[1][ct] = __builtin_amdgcn_mfma_f32_16x16x32_f16(b, afB[1][ki], acc[1][ct], 0, 0, 0);
        }

    // epilogue: packed 4-col stores per (rt, ct)
#pragma unroll
    for (int rt = 0; rt < 2; ++rt) {
        int row = row0 + rt * 16 + r;
        if (row < M) {
#pragma unroll
            for (int ct = 0; ct < 8; ++ct) {
                if constexpr (sizeof(TO) == 2) {
                    v4h p;
#pragma unroll
                    for (int j = 0; j < 4; ++j) {
                        float v = acc[rt][ct][j];
                        if (RELU) v = fmaxf(v, 0.f);
                        p[j] = (f16)v;
                    }
                    *(v4h*)((f16*)OUT + (size_t)row * DD + ct * 16 + cg * 4) = p;
                } else {
                    f32x4 p;
#pragma unroll
                    for (int j = 0; j < 4; ++j) {
                        float v = acc[rt][ct][j];
                        if (RELU) v = fmaxf(v, 0.f);
                        p[j] = v;
                    }
                    *(f32x4*)((float*)OUT + (size_t)row * DD + ct * 16 + cg * 4) = p;
                }
            }
        }
    }
}

// ---------------- launch ----------------

extern "C" void kernel_launch(void* const* d_in, const int* in_sizes, int n_in,
                              void* d_out, int out_size, void* d_ws, size_t ws_size,
                              hipStream_t stream) {
    const float* x = (const float*)d_in[0];
    const int* ei = (const int*)d_in[1];
    const float* Wp0 = (const float*)d_in[2];
    const float* bp0 = (const float*)d_in[3];
    const float* Wl0 = (const float*)d_in[4];
    const float* bl0 = (const float*)d_in[5];
    const float* Wr0 = (const float*)d_in[6];
    const float* Wp1 = (const float*)d_in[7];
    const float* bp1 = (const float*)d_in[8];
    const float* Wl1 = (const float*)d_in[9];
    const float* bl1 = (const float*)d_in[10];
    const float* Wr1 = (const float*)d_in[11];

    int N = in_sizes[0] / DD;
    int E = in_sizes[1] / 2;
    const int* src = ei;
    const int* dst = ei + E;

    // ---- workspace (~54.8MB, proven-safe footprint) ----
    // d_out timeline: [h: lower 25.6MB][x16: upper 25.6MB]; no kernel both
    // gathers from d_out and writes it; final dual_gemm reads only mean/y1
    // (ws) and rewrites all of d_out.
    char* ws = (char*)d_ws;
    size_t o = 0;
    auto alloc = [&](size_t bytes) {
        size_t r = o;
        o = (o + bytes + 255) & ~(size_t)255;
        return r;
    };
    f16* w16 = (f16*)(ws + alloc((size_t)6 * DD * DD * 2));
    int* cnt = (int*)(ws + alloc((size_t)N * 4));
    int* off = (int*)(ws + alloc((size_t)(N + 1) * 4));
    int NB = cdiv(N, 256);
    int* bsum = (int*)(ws + alloc((size_t)NB * 4));
    int* boff = (int*)(ws + alloc((size_t)NB * 4));
    int* csr = (int*)(ws + alloc((size_t)E * 4));
    f16* mean = (f16*)(ws + alloc((size_t)N * DD * 2));
    f16* y1 = (f16*)(ws + alloc((size_t)N * DD * 2));
    f16* h = (f16*)d_out;                                  // lower half of d_out
    f16* x16 = (f16*)((char*)d_out + (size_t)N * DD * 2);  // upper half of d_out
    (void)ws_size;

    // CSR build (shared by both layers)
    zero_kernel<<<NB, 256, 0, stream>>>(cnt, N);
    count_kernel<<<cdiv(E, 256), 256, 0, stream>>>(dst, E, cnt);
    scan1<<<NB, 256, 0, stream>>>(cnt, N, bsum);
    scan2<<<1, 512, 0, stream>>>(bsum, NB, boff);
    scan3<<<NB, 256, 0, stream>>>(cnt, boff, N, off);
    fill_kernel<<<cdiv(E, 256), 256, 0, stream>>>(src, dst, E, off, cnt, csr);

    // weights -> f16 once: order [Wp0, Wl0, Wr0, Wp1, Wl1, Wr1]
    cvt_w_kernel<<<96, 256, 0, stream>>>(Wp0, Wl0, Wr0, Wp1, Wl1, Wr1, w16);
    const f16* wp0 = w16 + 0 * 16384;
    const f16* wl0 = w16 + 1 * 16384;
    const f16* wr0 = w16 + 2 * 16384;
    const f16* wp1 = w16 + 3 * 16384;
    const f16* wl1 = w16 + 4 * 16384;
    const f16* wr1 = w16 + 5 * 16384;

    // x -> f16 once (separate kernel: fusing into proj was pipeline-negative, r6/r7)
    cvt_x_kernel<<<cdiv(N * DD / 8, 256), 256, 0, stream>>>(x, x16, N * DD / 8);

    int GB = cdiv(N, 128);
    // layer 1
    proj_gemm<<<GB, 256, 0, stream>>>(x16, wp0, bp0, h, N);
    aggregate_kernel<<<cdiv(N, 4), 256, 0, stream>>>(h, off, csr, mean, N);
    dual_gemm<f16, true><<<GB, 256, 0, stream>>>(mean, wl0, bl0, x16, wr0, y1, N);
    // layer 2
    proj_gemm<<<GB, 256, 0, stream>>>(y1, wp1, bp1, h, N);
    aggregate_kernel<<<cdiv(N, 4), 256, 0, stream>>>(h, off, csr, mean, N);
    dual_gemm<float, false><<<GB, 256, 0, stream>>>(mean, wl1, bl1, y1, wr1, (float*)d_out, N);
}

// Round 10
// 242.972 us; speedup vs baseline: 1.0378x; 1.0378x over previous
//
#include <hip/hip_runtime.h>

#define DD 128

typedef _Float16 f16;
typedef __attribute__((ext_vector_type(8))) _Float16 v8h;
typedef __attribute__((ext_vector_type(4))) _Float16 v4h;
typedef __attribute__((ext_vector_type(2))) _Float16 f16x2;
typedef __attribute__((ext_vector_type(4))) float f32x4;

static inline int cdiv(int a, int b) { return (a + b - 1) / b; }

// ---------------- small utility ----------------

__global__ __launch_bounds__(256) void zero_kernel(int* __restrict__ p, int n) {
    int i = blockIdx.x * 256 + threadIdx.x;
    if (i < n) p[i] = 0;
}

// ---------------- CSR build ----------------

__global__ __launch_bounds__(256) void count_kernel(const int* __restrict__ dst, int E,
                                                    int* __restrict__ cnt) {
    int e = blockIdx.x * 256 + threadIdx.x;
    if (e < E) atomicAdd(&cnt[dst[e]], 1);
}

__global__ __launch_bounds__(256) void scan1(const int* __restrict__ cnt, int N,
                                             int* __restrict__ bsum) {
    __shared__ int s[256];
    int i = blockIdx.x * 256 + threadIdx.x;
    s[threadIdx.x] = (i < N) ? cnt[i] : 0;
    __syncthreads();
    for (int off = 128; off > 0; off >>= 1) {
        if (threadIdx.x < off) s[threadIdx.x] += s[threadIdx.x + off];
        __syncthreads();
    }
    if (threadIdx.x == 0) bsum[blockIdx.x] = s[0];
}

__global__ __launch_bounds__(512) void scan2(const int* __restrict__ bsum, int NB,
                                             int* __restrict__ boff) {
    __shared__ int s[512];
    int t = threadIdx.x;
    int v = (t < NB) ? bsum[t] : 0;
    s[t] = v;
    __syncthreads();
    for (int off = 1; off < 512; off <<= 1) {
        int x = (t >= off) ? s[t - off] : 0;
        __syncthreads();
        s[t] += x;
        __syncthreads();
    }
    if (t < NB) boff[t] = s[t] - v;  // exclusive
}

__global__ __launch_bounds__(256) void scan3(const int* __restrict__ cnt,
                                             const int* __restrict__ boff, int N,
                                             int* __restrict__ off) {
    __shared__ int s[256];
    int t = threadIdx.x;
    int i = blockIdx.x * 256 + t;
    int v = (i < N) ? cnt[i] : 0;
    s[t] = v;
    __syncthreads();
    for (int o = 1; o < 256; o <<= 1) {
        int x = (t >= o) ? s[t - o] : 0;
        __syncthreads();
        s[t] += x;
        __syncthreads();
    }
    int excl = s[t] - v + boff[blockIdx.x];
    if (i < N) off[i] = excl;
    if (i == N - 1) off[N] = excl + v;
}

__global__ __launch_bounds__(256) void fill_kernel(const int* __restrict__ src,
                                                   const int* __restrict__ dst, int E,
                                                   const int* __restrict__ off,
                                                   int* __restrict__ cnt,
                                                   int* __restrict__ csr) {
    int e = blockIdx.x * 256 + threadIdx.x;
    if (e < E) {
        int d = dst[e];
        int p = atomicSub(&cnt[d], 1) - 1;  // unique slot within [0, deg)
        csr[off[d] + p] = src[e];
    }
}

// ---------------- fp32 -> f16 conversions ----------------

__global__ __launch_bounds__(256) void cvt_w_kernel(const float* __restrict__ W0,
                                                    const float* __restrict__ W1,
                                                    const float* __restrict__ W2,
                                                    const float* __restrict__ W3,
                                                    const float* __restrict__ W4,
                                                    const float* __restrict__ W5,
                                                    f16* __restrict__ out) {
    int mat = blockIdx.x >> 4;  // 16 blocks per matrix (16384 elems / (256*4))
    const float* W = mat == 0 ? W0 : mat == 1 ? W1 : mat == 2 ? W2
                   : mat == 3 ? W3 : mat == 4 ? W4 : W5;
    int base = (blockIdx.x & 15) * 1024 + threadIdx.x * 4;
    float4 v = *(const float4*)(W + base);
    v4h o;
    o[0] = (f16)v.x; o[1] = (f16)v.y; o[2] = (f16)v.z; o[3] = (f16)v.w;
    *(v4h*)(out + mat * 16384 + base) = o;
}

__global__ __launch_bounds__(256) void cvt_x_kernel(const float* __restrict__ x,
                                                    f16* __restrict__ out, int n8) {
    int i = blockIdx.x * 256 + threadIdx.x;
    if (i >= n8) return;
    float4 a = *(const float4*)(x + (size_t)i * 8);
    float4 b = *(const float4*)(x + (size_t)i * 8 + 4);
    v8h r;
    r[0] = (f16)a.x; r[1] = (f16)a.y; r[2] = (f16)a.z; r[3] = (f16)a.w;
    r[4] = (f16)b.x; r[5] = (f16)b.y; r[6] = (f16)b.z; r[7] = (f16)b.w;
    *(v8h*)(out + (size_t)i * 8) = r;
}

// ---------------- aggregation: mean of gathered h rows (round-4 exact) ----------------
// Wave per node; 4 groups x 16 lanes; each group gathers a full 256B row.
// Simple inner loop; explicit pipelining (r6), batching (r7), grid-stride (r8)
// all regressed.

__global__ __launch_bounds__(256) void aggregate_kernel(const f16* __restrict__ h,
                                                        const int* __restrict__ off,
                                                        const int* __restrict__ csr,
                                                        f16* __restrict__ mean, int N) {
    int n = blockIdx.x * 4 + (threadIdx.x >> 6);
    int l = threadIdx.x & 63;
    int g = l >> 4, c = l & 15;
    if (n >= N) return;
    int s = off[n], e = off[n + 1];
    float acc[8] = {0.f, 0.f, 0.f, 0.f, 0.f, 0.f, 0.f, 0.f};
    for (int i = s + g; i < e; i += 4) {
        int idx = csr[i];
        v8h v = *(const v8h*)(h + (size_t)idx * DD + c * 8);
#pragma unroll
        for (int j = 0; j < 8; ++j) acc[j] += (float)v[j];
    }
#pragma unroll
    for (int j = 0; j < 8; ++j) {
        acc[j] += __shfl_xor(acc[j], 16);
        acc[j] += __shfl_xor(acc[j], 32);
    }
    int deg = e - s;
    float inv = 1.0f / (float)(deg > 0 ? deg : 1);
    if (g == 0) {
        v8h o;
#pragma unroll
        for (int j = 0; j < 8; ++j) o[j] = (f16)(acc[j] * inv);
        *(v8h*)(mean + (size_t)n * DD + c * 8) = o;
    }
}

// ---------------- shared GEMM helpers (round-4 exact, non-transposed) ----------------
// mfma_f32_16x16x32_f16: A frag lane l -> A[row=l&15][k=(l>>4)*8+j] (8 contig f16)
//                        B frag lane l -> W[col=l&15][k=(l>>4)*8+j] (8 contig f16)
//                        D lane l reg j -> D[row=(l>>4)*4+j][col=l&15]

__device__ inline void stage_w(const f16* __restrict__ Wg, f16* __restrict__ smem, int t) {
#pragma unroll
    for (int i = 0; i < 8; ++i) {
        int idx16 = i * 256 + t;
        int col = idx16 >> 4, c16 = idx16 & 15;
        int sc = c16 ^ (col & 7);
        uint4 v = *(const uint4*)(Wg + idx16 * 8);
        *(uint4*)(smem + col * DD + sc * 8) = v;
    }
}

__device__ inline v8h read_b(const f16* __restrict__ smem, int ct, int ki, int l) {
    int col = ct * 16 + (l & 15);
    int c16 = ki * 4 + (l >> 4);
    int sc = c16 ^ (col & 7);
    return *(const v8h*)(smem + col * DD + sc * 8);
}

__device__ inline v8h load_frag16(const f16* __restrict__ A, int row, int kb, int M) {
    if (row >= M) {
        v8h z = {};
        return z;
    }
    return *(const v8h*)(A + (size_t)row * DD + kb);
}

// ---------------- projection GEMM: OUT = relu(A @ W^T + bias) ----------------

__global__ __launch_bounds__(256) void proj_gemm(const f16* __restrict__ A,
                                                 const f16* __restrict__ W1,
                                                 const float* __restrict__ bias,
                                                 f16* __restrict__ OUT, int M) {
    __shared__ f16 WS[DD * DD];
    int t = threadIdx.x, l = t & 63, w = t >> 6;
    int row0 = blockIdx.x * 128 + w * 32;
    int r = l & 15, cg = l >> 4;

    stage_w(W1, WS, t);

    v8h af[2][4];
#pragma unroll
    for (int rt = 0; rt < 2; ++rt)
#pragma unroll
        for (int ki = 0; ki < 4; ++ki)
            af[rt][ki] = load_frag16(A, row0 + rt * 16 + r, ki * 32 + cg * 8, M);
    __syncthreads();

    f32x4 acc[2][8];
#pragma unroll
    for (int ct = 0; ct < 8; ++ct) {
        float bv = bias[ct * 16 + r];
        f32x4 b4 = {bv, bv, bv, bv};
        acc[0][ct] = b4;
        acc[1][ct] = b4;
    }

#pragma unroll
    for (int ct = 0; ct < 8; ++ct)
#pragma unroll
        for (int ki = 0; ki < 4; ++ki) {
            v8h b = read_b(WS, ct, ki, l);
            acc[0][ct] = __builtin_amdgcn_mfma_f32_16x16x32_f16(af[0][ki], b, acc[0][ct], 0, 0, 0);
            acc[1][ct] = __builtin_amdgcn_mfma_f32_16x16x32_f16(af[1][ki], b, acc[1][ct], 0, 0, 0);
        }

#pragma unroll
    for (int rt = 0; rt < 2; ++rt)
#pragma unroll
        for (int ct = 0; ct < 8; ++ct)
#pragma unroll
            for (int j = 0; j < 4; ++j) {
                int row = row0 + rt * 16 + cg * 4 + j;
                if (row < M)
                    OUT[(size_t)row * DD + ct * 16 + r] = (f16)fmaxf(acc[rt][ct][j], 0.f);
            }
}

// ---------------- dual GEMM (round-4 exact): OUT = act(A@Wl^T + bias + B@Wr^T) ----------------

template <typename TO, bool RELU>
__global__ __launch_bounds__(256) void dual_gemm(const f16* __restrict__ A,
                                                 const f16* __restrict__ Wl,
                                                 const float* __restrict__ bias,
                                                 const f16* __restrict__ B,
                                                 const f16* __restrict__ Wr,
                                                 TO* __restrict__ OUT, int M) {
    __shared__ f16 WS[DD * DD];
    int t = threadIdx.x, l = t & 63, w = t >> 6;
    int row0 = blockIdx.x * 128 + w * 32;
    int r = l & 15, cg = l >> 4;

    stage_w(Wl, WS, t);

    v8h afA[2][4], afB[2][4];
#pragma unroll
    for (int rt = 0; rt < 2; ++rt)
#pragma unroll
        for (int ki = 0; ki < 4; ++ki) {
            int row = row0 + rt * 16 + r, kb = ki * 32 + cg * 8;
            afA[rt][ki] = load_frag16(A, row, kb, M);
            afB[rt][ki] = load_frag16(B, row, kb, M);
        }
    __syncthreads();

    f32x4 acc[2][8];
#pragma unroll
    for (int ct = 0; ct < 8; ++ct) {
        float bv = bias[ct * 16 + r];
        f32x4 b4 = {bv, bv, bv, bv};
        acc[0][ct] = b4;
        acc[1][ct] = b4;
    }

#pragma unroll
    for (int ct = 0; ct < 8; ++ct)
#pragma unroll
        for (int ki = 0; ki < 4; ++ki) {
            v8h b = read_b(WS, ct, ki, l);
            acc[0][ct] = __builtin_amdgcn_mfma_f32_16x16x32_f16(afA[0][ki], b, acc[0][ct], 0, 0, 0);
            acc[1][ct] = __builtin_amdgcn_mfma_f32_16x16x32_f16(afA[1][ki], b, acc[1][ct], 0, 0, 0);
        }

    __syncthreads();
    stage_w(Wr, WS, t);
    __syncthreads();

#pragma unroll
    for (int ct = 0; ct < 8; ++ct)
#pragma unroll
        for (int ki = 0; ki < 4; ++ki) {
            v8h b = read_b(WS, ct, ki, l);
            acc[0][ct] = __builtin_amdgcn_mfma_f32_16x16x32_f16(afB[0][ki], b, acc[0][ct], 0, 0, 0);
            acc[1][ct] = __builtin_amdgcn_mfma_f32_16x16x32_f16(afB[1][ki], b, acc[1][ct], 0, 0, 0);
        }

#pragma unroll
    for (int rt = 0; rt < 2; ++rt)
#pragma unroll
        for (int ct = 0; ct < 8; ++ct)
#pragma unroll
            for (int j = 0; j < 4; ++j) {
                int row = row0 + rt * 16 + cg * 4 + j;
                if (row < M) {
                    float v = acc[rt][ct][j];
                    if (RELU) v = fmaxf(v, 0.f);
                    OUT[(size_t)row * DD + ct * 16 + r] = (TO)v;
                }
            }
}

// ---------------- fused dual GEMM + next-layer projection ----------------
// Y = relu(A@Wl^T + bl + B@Wr^T)  (y1, stored)
// H = relu(Y@Wp^T + bp)           (h2, stored) — consumes f16-rounded Y from
// registers via an LDS transpose (D-frag -> A-frag), saving the proj2 launch,
// its y1 re-read and W staging. WS (32KB) is reused: Wl -> Wr -> Y^T -> Wp.
// Transpose layout: f16 addr = brow*128 + ((c16 ^ (brow&7))<<3) + (col&7)
// (chunk-XOR swizzle -> 2-way conflicts max on the v8h reads, free per m136).

__global__ __launch_bounds__(256) void dualproj_gemm(const f16* __restrict__ A,
                                                     const f16* __restrict__ Wl,
                                                     const float* __restrict__ bl,
                                                     const f16* __restrict__ B,
                                                     const f16* __restrict__ Wr,
                                                     f16* __restrict__ Y,
                                                     const f16* __restrict__ Wp,
                                                     const float* __restrict__ bp,
                                                     f16* __restrict__ H, int M) {
    __shared__ f16 WS[DD * DD];
    int t = threadIdx.x, l = t & 63, w = t >> 6;
    int row0 = blockIdx.x * 128 + w * 32;
    int r = l & 15, cg = l >> 4;

    // ---- phase 1: dual GEMM (identical to dual_gemm) ----
    stage_w(Wl, WS, t);

    v8h afA[2][4], afB[2][4];
#pragma unroll
    for (int rt = 0; rt < 2; ++rt)
#pragma unroll
        for (int ki = 0; ki < 4; ++ki) {
            int row = row0 + rt * 16 + r, kb = ki * 32 + cg * 8;
            afA[rt][ki] = load_frag16(A, row, kb, M);
            afB[rt][ki] = load_frag16(B, row, kb, M);
        }
    __syncthreads();

    f32x4 acc[2][8];
#pragma unroll
    for (int ct = 0; ct < 8; ++ct) {
        float bv = bl[ct * 16 + r];
        f32x4 b4 = {bv, bv, bv, bv};
        acc[0][ct] = b4;
        acc[1][ct] = b4;
    }

#pragma unroll
    for (int ct = 0; ct < 8; ++ct)
#pragma unroll
        for (int ki = 0; ki < 4; ++ki) {
            v8h b = read_b(WS, ct, ki, l);
            acc[0][ct] = __builtin_amdgcn_mfma_f32_16x16x32_f16(afA[0][ki], b, acc[0][ct], 0, 0, 0);
            acc[1][ct] = __builtin_amdgcn_mfma_f32_16x16x32_f16(afA[1][ki], b, acc[1][ct], 0, 0, 0);
        }

    __syncthreads();
    stage_w(Wr, WS, t);
    __syncthreads();

#pragma unroll
    for (int ct = 0; ct < 8; ++ct)
#pragma unroll
        for (int ki = 0; ki < 4; ++ki) {
            v8h b = read_b(WS, ct, ki, l);
            acc[0][ct] = __builtin_amdgcn_mfma_f32_16x16x32_f16(afB[0][ki], b, acc[0][ct], 0, 0, 0);
            acc[1][ct] = __builtin_amdgcn_mfma_f32_16x16x32_f16(afB[1][ki], b, acc[1][ct], 0, 0, 0);
        }

    // ---- relu + store Y + write transposed f16 tile into WS ----
    __syncthreads();  // all waves done reading Wr before overwriting WS
#pragma unroll
    for (int rt = 0; rt < 2; ++rt)
#pragma unroll
        for (int ct = 0; ct < 8; ++ct)
#pragma unroll
            for (int j = 0; j < 4; ++j) {
                int brow = w * 32 + rt * 16 + cg * 4 + j;  // block-local row
                int col = ct * 16 + r;
                f16 hv = (f16)fmaxf(acc[rt][ct][j], 0.f);
                int c16 = col >> 3;
                WS[brow * DD + (((c16 ^ (brow & 7)) << 3) | (col & 7))] = hv;
                int grow = blockIdx.x * 128 + brow;
                if (grow < M) Y[(size_t)grow * DD + col] = hv;
            }
    __syncthreads();

    // ---- read phase-2 A fragments from the transposed tile ----
    v8h af2[2][4];
#pragma unroll
    for (int rt = 0; rt < 2; ++rt)
#pragma unroll
        for (int ki = 0; ki < 4; ++ki) {
            int brow = w * 32 + rt * 16 + r;
            af2[rt][ki] = *(const v8h*)(WS + brow * DD + (((ki * 4 + cg) ^ (brow & 7)) << 3));
        }
    __syncthreads();  // all waves done reading Y^T before restaging

    // ---- phase 2: projection GEMM on in-register Y ----
    stage_w(Wp, WS, t);

    f32x4 acc2[2][8];
#pragma unroll
    for (int ct = 0; ct < 8; ++ct) {
        float bv = bp[ct * 16 + r];
        f32x4 b4 = {bv, bv, bv, bv};
        acc2[0][ct] = b4;
        acc2[1][ct] = b4;
    }
    __syncthreads();

#pragma unroll
    for (int ct = 0; ct < 8; ++ct)
#pragma unroll
        for (int ki = 0; ki < 4; ++ki) {
            v8h b = read_b(WS, ct, ki, l);
            acc2[0][ct] = __builtin_amdgcn_mfma_f32_16x16x32_f16(af2[0][ki], b, acc2[0][ct], 0, 0, 0);
            acc2[1][ct] = __builtin_amdgcn_mfma_f32_16x16x32_f16(af2[1][ki], b, acc2[1][ct], 0, 0, 0);
        }

#pragma unroll
    for (int rt = 0; rt < 2; ++rt)
#pragma unroll
        for (int ct = 0; ct < 8; ++ct)
#pragma unroll
            for (int j = 0; j < 4; ++j) {
                int row = row0 + rt * 16 + cg * 4 + j;
                if (row < M)
                    H[(size_t)row * DD + ct * 16 + r] = (f16)fmaxf(acc2[rt][ct][j], 0.f);
            }
}

// ---------------- launch ----------------

extern "C" void kernel_launch(void* const* d_in, const int* in_sizes, int n_in,
                              void* d_out, int out_size, void* d_ws, size_t ws_size,
                              hipStream_t stream) {
    const float* x = (const float*)d_in[0];
    const int* ei = (const int*)d_in[1];
    const float* Wp0 = (const float*)d_in[2];
    const float* bp0 = (const float*)d_in[3];
    const float* Wl0 = (const float*)d_in[4];
    const float* bl0 = (const float*)d_in[5];
    const float* Wr0 = (const float*)d_in[6];
    const float* Wp1 = (const float*)d_in[7];
    const float* bp1 = (const float*)d_in[8];
    const float* Wl1 = (const float*)d_in[9];
    const float* bl1 = (const float*)d_in[10];
    const float* Wr1 = (const float*)d_in[11];

    int N = in_sizes[0] / DD;
    int E = in_sizes[1] / 2;
    const int* src = ei;
    const int* dst = ei + E;

    // ---- workspace (~54.8MB, proven-safe footprint) ----
    // d_out timeline: [h: lower 25.6MB][x16: upper 25.6MB]; dualproj reads
    // x16 (upper) and writes h (lower) — disjoint halves; final dual_gemm
    // reads only mean/y1 (ws) and rewrites all of d_out.
    char* ws = (char*)d_ws;
    size_t o = 0;
    auto alloc = [&](size_t bytes) {
        size_t r = o;
        o = (o + bytes + 255) & ~(size_t)255;
        return r;
    };
    f16* w16 = (f16*)(ws + alloc((size_t)6 * DD * DD * 2));
    int* cnt = (int*)(ws + alloc((size_t)N * 4));
    int* off = (int*)(ws + alloc((size_t)(N + 1) * 4));
    int NB = cdiv(N, 256);
    int* bsum = (int*)(ws + alloc((size_t)NB * 4));
    int* boff = (int*)(ws + alloc((size_t)NB * 4));
    int* csr = (int*)(ws + alloc((size_t)E * 4));
    f16* mean = (f16*)(ws + alloc((size_t)N * DD * 2));
    f16* y1 = (f16*)(ws + alloc((size_t)N * DD * 2));
    f16* h = (f16*)d_out;                                  // lower half of d_out
    f16* x16 = (f16*)((char*)d_out + (size_t)N * DD * 2);  // upper half of d_out
    (void)ws_size;

    // CSR build (shared by both layers)
    zero_kernel<<<NB, 256, 0, stream>>>(cnt, N);
    count_kernel<<<cdiv(E, 256), 256, 0, stream>>>(dst, E, cnt);
    scan1<<<NB, 256, 0, stream>>>(cnt, N, bsum);
    scan2<<<1, 512, 0, stream>>>(bsum, NB, boff);
    scan3<<<NB, 256, 0, stream>>>(cnt, boff, N, off);
    fill_kernel<<<cdiv(E, 256), 256, 0, stream>>>(src, dst, E, off, cnt, csr);

    // weights -> f16 once: order [Wp0, Wl0, Wr0, Wp1, Wl1, Wr1]
    cvt_w_kernel<<<96, 256, 0, stream>>>(Wp0, Wl0, Wr0, Wp1, Wl1, Wr1, w16);
    const f16* wp0 = w16 + 0 * 16384;
    const f16* wl0 = w16 + 1 * 16384;
    const f16* wr0 = w16 + 2 * 16384;
    const f16* wp1 = w16 + 3 * 16384;
    const f16* wl1 = w16 + 4 * 16384;
    const f16* wr1 = w16 + 5 * 16384;

    // x -> f16 once (separate kernel; fusing into proj was pipeline-negative)
    cvt_x_kernel<<<cdiv(N * DD / 8, 256), 256, 0, stream>>>(x, x16, N * DD / 8);

    int GB = cdiv(N, 128);
    // layer 1
    proj_gemm<<<GB, 256, 0, stream>>>(x16, wp0, bp0, h, N);
    aggregate_kernel<<<cdiv(N, 4), 256, 0, stream>>>(h, off, csr, mean, N);
    // fused: y1 = relu(mean@Wl0^T + bl0 + x16@Wr0^T); h = relu(y1@Wp1^T + bp1)
    dualproj_gemm<<<GB, 256, 0, stream>>>(mean, wl0, bl0, x16, wr0, y1, wp1, bp1, h, N);
    // layer 2
    aggregate_kernel<<<cdiv(N, 4), 256, 0, stream>>>(h, off, csr, mean, N);
    dual_gemm<float, false><<<GB, 256, 0, stream>>>(mean, wl1, bl1, y1, wr1, (float*)d_out, N);
}